// Round 1
// baseline (234.152 us; speedup 1.0000x reference)
//
#include <hip/hip_runtime.h>
#include <hip/hip_cooperative_groups.h>
#include <cmath>

namespace cg = cooperative_groups;

namespace {
constexpr int NELEM  = 50000;
constexpr int NSYN   = 500;
constexpr int NQ4    = 125;                 // NSYN/4
constexpr int T      = 1024;
constexpr int SBLK   = 49;                  // 49*1024 = 50176 >= NELEM
constexpr int SLOTS  = SBLK * T;            // 50176
constexpr int CMAXC  = (NELEM - 1) >> 6;    // 781 (64-elem chunks)
constexpr int NCH_PAD = 784;
constexpr int MAXSEG = 4096;
constexpr int NGRP   = NELEM / 8;           // 6250
constexpr double DELTA_D = 1.0e-3;
constexpr double THETA_D = 1.0;
constexpr float  DECAY_F = 0.90483741803595957311f;  // float32(exp(-1/10))
}

struct WS {
    double2 rq[SLOTS];                       // (R_i, Q_i)  R=Q-theta/P
    double  gAm[64], gAg[64], gAi[64];       // 49 block aggregates (affine)
    double  gPp[64], gPq[64];                // 49 block aggregates (p,q)
    double  gmaxR[1024];                     // per-64-chunk max R
    double  gbndQ[MAXSEG];
    int     gbnd[MAXSEG];
    int     gnseg;
    int     pad;
    float   swv[SLOTS];
    float   iwv[SLOTS];
};  // ~1.3 MB

// ---------------- K1: per-timestep weighted row sums (natural layout) ----------------
__global__ __launch_bounds__(256) void k_rowdot(
    const float* __restrict__ spikes,
    const float* __restrict__ w,
    const float* __restrict__ vrev,
    float* __restrict__ swv,
    float* __restrict__ iwv)
{
    const int lane = threadIdx.x & 63;
    const int wv   = threadIdx.x >> 6;
    const int rg   = blockIdx.x * 4 + wv;
    if (rg >= NGRP) return;
    const int row0 = rg * 8;

    const float4* __restrict__ w4 = reinterpret_cast<const float4*>(w);
    const float4* __restrict__ r4 = reinterpret_cast<const float4*>(vrev);
    const int j1 = lane;
    const int j2 = lane + 64;
    const bool has2 = (j2 < NQ4);
    float4 a1 = w4[j1], r1 = r4[j1];
    float4 aw1 = make_float4(fabsf(a1.x), fabsf(a1.y), fabsf(a1.z), fabsf(a1.w));
    float4 ar1 = make_float4(aw1.x * r1.x, aw1.y * r1.y, aw1.z * r1.z, aw1.w * r1.w);
    float4 aw2 = make_float4(0.f, 0.f, 0.f, 0.f), ar2 = aw2;
    if (has2) {
        float4 a2 = w4[j2], r2 = r4[j2];
        aw2 = make_float4(fabsf(a2.x), fabsf(a2.y), fabsf(a2.z), fabsf(a2.w));
        ar2 = make_float4(aw2.x * r2.x, aw2.y * r2.y, aw2.z * r2.z, aw2.w * r2.w);
    }

    float sp[8], ip[8];
#pragma unroll
    for (int r = 0; r < 8; ++r) {
        const float4* __restrict__ srow =
            reinterpret_cast<const float4*>(spikes + (size_t)(row0 + r) * NSYN);
        float4 s1 = srow[j1];
        float a = s1.x * aw1.x + s1.y * aw1.y + s1.z * aw1.z + s1.w * aw1.w;
        float b = s1.x * ar1.x + s1.y * ar1.y + s1.z * ar1.z + s1.w * ar1.w;
        if (has2) {
            float4 s2 = srow[j2];
            a += s2.x * aw2.x + s2.y * aw2.y + s2.z * aw2.z + s2.w * aw2.w;
            b += s2.x * ar2.x + s2.y * ar2.y + s2.z * ar2.z + s2.w * ar2.w;
        }
        sp[r] = a; ip[r] = b;
    }
#pragma unroll
    for (int d = 32; d > 0; d >>= 1) {
#pragma unroll
        for (int r = 0; r < 8; ++r) {
            sp[r] += __shfl_xor(sp[r], d);
            ip[r] += __shfl_xor(ip[r], d);
        }
    }
    if (lane == 0) {
        *reinterpret_cast<float4*>(swv + row0)     = make_float4(sp[0], sp[1], sp[2], sp[3]);
        *reinterpret_cast<float4*>(swv + row0 + 4) = make_float4(sp[4], sp[5], sp[6], sp[7]);
        *reinterpret_cast<float4*>(iwv + row0)     = make_float4(ip[0], ip[1], ip[2], ip[3]);
        *reinterpret_cast<float4*>(iwv + row0 + 4) = make_float4(ip[4], ip[5], ip[6], ip[7]);
    }
}

// ---------------- K2: fused scans + search + fill (cooperative, 49 blocks) ----------------
__global__ __launch_bounds__(1024) void k_fused(WS* __restrict__ ws, float* __restrict__ out)
{
    cg::grid_group grid = cg::this_grid();
    const int tid = threadIdx.x, lane = tid & 63, wv = tid >> 6, blk = blockIdx.x;
    const int idx = blk * T + tid;
    const bool live = (idx < NELEM);
    const double decay = (double)DECAY_F;

    __shared__ double s_a[16], s_b[16], s_c[16];
    __shared__ double s_qg0, s_qi0, s_qp0, s_qq0;
    __shared__ double smax[NCH_PAD];
    __shared__ int    sb[MAXSEG];
    __shared__ double sq[MAXSEG];
    __shared__ int    s_nseg;

    // ======== Phase B: block-local affine (m,g,i) scan ========
    double s = live ? (double)ws->swv[idx] : 0.0;
    double t = live ? (double)ws->iwv[idx] : 0.0;
    double m_in = live ? decay : 1.0;
    double g_in = live ? s * decay : 0.0;
    double i_in = live ? t * decay : 0.0;
#pragma unroll
    for (int d = 1; d < 64; d <<= 1) {
        double pm = __shfl_up(m_in, d);
        double pg = __shfl_up(g_in, d);
        double pi = __shfl_up(i_in, d);
        if (lane >= d) {
            g_in = m_in * pg + g_in;
            i_in = m_in * pi + i_in;
            m_in = pm * m_in;
        }
    }
    if (lane == 63) { s_a[wv] = m_in; s_b[wv] = g_in; s_c[wv] = i_in; }
    __syncthreads();
    if (wv == 0) {
        double wm = (lane < 16) ? s_a[lane] : 1.0;
        double wg = (lane < 16) ? s_b[lane] : 0.0;
        double wi = (lane < 16) ? s_c[lane] : 0.0;
#pragma unroll
        for (int d = 1; d < 16; d <<= 1) {
            double pm = __shfl_up(wm, d);
            double pg = __shfl_up(wg, d);
            double pi = __shfl_up(wi, d);
            if (lane >= d) {
                wg = wm * pg + wg;
                wi = wm * pi + wi;
                wm = pm * wm;
            }
        }
        if (lane < 16) { s_a[lane] = wm; s_b[lane] = wg; s_c[lane] = wi; }
        if (lane == 15) { ws->gAm[blk] = wm; ws->gAg[blk] = wg; ws->gAi[blk] = wi; }
    }
    __syncthreads();
    double em = __shfl_up(m_in, 1), eg = __shfl_up(g_in, 1), ei = __shfl_up(i_in, 1);
    if (lane == 0) { em = 1.0; eg = 0.0; ei = 0.0; }
    if (wv > 0) {
        double qm = s_a[wv - 1], qg = s_b[wv - 1], qi = s_c[wv - 1];
        eg = em * qg + eg;
        ei = em * qi + ei;
        em = qm * em;
    }

    grid.sync();

    // ======== Phase D: redundant 49-aggregate affine scan + (p,q) block scan ========
    if (wv == 0) {
        double am = (lane < SBLK) ? ws->gAm[lane] : 1.0;
        double ag = (lane < SBLK) ? ws->gAg[lane] : 0.0;
        double ai = (lane < SBLK) ? ws->gAi[lane] : 0.0;
#pragma unroll
        for (int d = 1; d < 64; d <<= 1) {
            double pm = __shfl_up(am, d);
            double pg = __shfl_up(ag, d);
            double pi = __shfl_up(ai, d);
            if (lane >= d) {
                ag = am * pg + ag;
                ai = am * pi + ai;
                am = pm * am;
            }
        }
        double zg = __shfl_up(ag, 1), zi = __shfl_up(ai, 1);
        if (lane == 0) { zg = 0.0; zi = 0.0; }
        if (lane == blk) { s_qg0 = zg; s_qi0 = zi; }
    }
    __syncthreads();

    double Eg = em * s_qg0 + eg;        // global-exclusive exp traces entering idx
    double Ei = em * s_qi0 + ei;
    double p_in = 1.0, q_in = 0.0;
    if (live) {
        double aa = DELTA_D * (1.0 + Eg);
        double om = 1.0 - aa;
        p_in = om;
        q_in = (DELTA_D * Ei) / om;
    }
#pragma unroll
    for (int d = 1; d < 64; d <<= 1) {
        double pp = __shfl_up(p_in, d);
        double pq = __shfl_up(q_in, d);
        if (lane >= d) {
            q_in = pq + q_in / pp;
            p_in = pp * p_in;
        }
    }
    if (lane == 63) { s_a[wv] = p_in; s_b[wv] = q_in; }
    __syncthreads();
    if (wv == 0) {
        double wp = (lane < 16) ? s_a[lane] : 1.0;
        double wq = (lane < 16) ? s_b[lane] : 0.0;
#pragma unroll
        for (int d = 1; d < 16; d <<= 1) {
            double pp = __shfl_up(wp, d);
            double pq = __shfl_up(wq, d);
            if (lane >= d) {
                wq = pq + wq / pp;
                wp = pp * wp;
            }
        }
        if (lane < 16) { s_a[lane] = wp; s_b[lane] = wq; }
        if (lane == 15) { ws->gPp[blk] = wp; ws->gPq[blk] = wq; }
    }
    __syncthreads();
    double ep = __shfl_up(p_in, 1), eq = __shfl_up(q_in, 1);
    if (lane == 0) { ep = 1.0; eq = 0.0; }
    if (wv > 0) {
        double ap2 = s_a[wv - 1], aq2 = s_b[wv - 1];
        eq = aq2 + eq / ap2;
        ep = ap2 * ep;
    }

    grid.sync();

    // ======== Phase F: redundant 49-aggregate (p,q) scan + apply ========
    if (wv == 0) {
        double ap = (lane < SBLK) ? ws->gPp[lane] : 1.0;
        double aq = (lane < SBLK) ? ws->gPq[lane] : 0.0;
#pragma unroll
        for (int d = 1; d < 64; d <<= 1) {
            double pp = __shfl_up(ap, d);
            double pq = __shfl_up(aq, d);
            if (lane >= d) {
                aq = pq + aq / pp;
                ap = pp * ap;
            }
        }
        double zp = __shfl_up(ap, 1), zq = __shfl_up(aq, 1);
        if (lane == 0) { zp = 1.0; zq = 0.0; }
        if (lane == blk) { s_qp0 = zp; s_qq0 = zq; }
    }
    __syncthreads();
    double Q = s_qq0 + eq / s_qp0;
    double P = s_qp0 * ep;
    double R = live ? (Q - THETA_D / P) : -1.0e308;
    ws->rq[idx] = make_double2(R, Q);
    double mR = R;
#pragma unroll
    for (int d = 32; d > 0; d >>= 1) mR = fmax(mR, __shfl_xor(mR, d));
    if (lane == 0) ws->gmaxR[idx >> 6] = mR;

    grid.sync();

    // ======== Phase G: serial segment search (block 0 wave 0) + XCD0 prewarm ========
    if (blk == 0) {
        for (int c = tid; c < NCH_PAD; c += T)
            smax[c] = (c <= CMAXC) ? ws->gmaxR[c] : -1.0e308;
        __syncthreads();
        if (tid < 64) {
            int nseg = 1;
            if (lane == 0) { ws->gbnd[0] = 0; ws->gbndQ[0] = 0.0; }
            double Qr = 0.0;
            int pos = 1;
            while (pos < NELEM && nseg < MAXSEG) {
                int c = pos >> 6;
                int i0 = -1;
                double Qnb = 0.0;
                while (true) {
                    int cf = -1;
                    for (int cb = c; cb <= CMAXC; cb += 64) {
                        int cc = cb + lane;
                        bool qy = (cc <= CMAXC) && (smax[cc] >= Qr);
                        unsigned long long m = __ballot(qy);
                        if (m) { cf = cb + __builtin_ctzll(m); break; }
                    }
                    if (cf < 0) break;
                    int i = (cf << 6) + lane;
                    bool valid = (i >= pos) && (i < NELEM);
                    double2 rv = valid ? ws->rq[i] : make_double2(-1.0e308, 0.0);
                    unsigned long long m2 = __ballot(valid && (rv.x >= Qr));
                    if (m2) {
                        int r = __builtin_ctzll(m2);
                        i0 = (cf << 6) + r;
                        if (r < 63) Qnb = __shfl(rv.y, r + 1);   // Q[i0+1] from same chunk load
                        break;
                    }
                    c = cf + 1;               // chunk max came from masked-out elems
                    if (c > CMAXC) break;
                }
                if (i0 < 0) break;
                int nb = i0 + 1;              // reset lands at nb
                if (nb >= NELEM) break;
                if ((i0 & 63) == 63) Qnb = ws->rq[nb].y;  // rare: boundary straddle
                Qr = Qnb;
                if (lane == 0) { ws->gbnd[nseg] = nb; ws->gbndQ[nseg] = Qr; }
                nseg++;
                pos = nb + 1;
            }
            if (lane == 0) ws->gnseg = nseg;
        } else {
            // block 0, tid>=64: prewarm slice 0 of rq into this XCD's L2
            double acc = 0.0;
            for (int i = tid; i < NELEM; i += 7 * T) acc += ws->rq[i].x;
            asm volatile("" :: "v"((float)acc));
        }
    } else if ((blk & 7) == 0) {
        // blocks 8,16,24,32,40,48: co-resident on XCD0's dispatch stripe -> prewarm
        const int p = blk >> 3;
        double acc = 0.0;
        for (int i = p * T + tid; i < NELEM; i += 7 * T) acc += ws->rq[i].x;
        asm volatile("" :: "v"((float)acc));
    }

    grid.sync();

    // ======== Phase H: parallel fill from register P,Q ========
    if (tid == 0) s_nseg = ws->gnseg;
    __syncthreads();
    const int nseg = s_nseg;
    for (int i2 = tid; i2 < nseg; i2 += T) { sb[i2] = ws->gbnd[i2]; sq[i2] = ws->gbndQ[i2]; }
    __syncthreads();
    if (live) {
        int lo = 0, hi = nseg - 1;
        while (lo < hi) {
            int mid = (lo + hi + 1) >> 1;
            if (sb[mid] <= idx) lo = mid; else hi = mid - 1;
        }
        out[idx] = (idx == sb[lo]) ? 0.0f : (float)(P * (Q - sq[lo]));
    }
}

extern "C" void kernel_launch(void* const* d_in, const int* in_sizes, int n_in,
                              void* d_out, int out_size, void* d_ws, size_t ws_size,
                              hipStream_t stream) {
    const float* spikes = (const float*)d_in[0];
    const float* w      = (const float*)d_in[1];
    const float* vrev   = (const float*)d_in[2];
    float* out = (float*)d_out;
    WS* ws = (WS*)d_ws;

    hipLaunchKernelGGL(k_rowdot, dim3((NGRP + 3) / 4), dim3(256), 0, stream,
                       spikes, w, vrev, ws->swv, ws->iwv);

    WS* wsp = ws; float* outp = out;
    void* args[2] = { (void*)&wsp, (void*)&outp };
    (void)hipLaunchCooperativeKernel((const void*)k_fused, dim3(SBLK), dim3(T),
                                     args, 0, stream);
}

// Round 2
// 196.976 us; speedup vs baseline: 1.1887x; 1.1887x over previous
//
#include <hip/hip_runtime.h>
#include <cmath>

namespace {
constexpr int NELEM  = 50000;
constexpr int NSYN   = 500;
constexpr int NQ4    = 125;                 // NSYN/4
constexpr int T      = 1024;
constexpr int SBLK   = 49;                  // 49*1024 = 50176 >= NELEM
constexpr int SLOTS  = SBLK * T;            // 50176
constexpr int CMAXC  = (NELEM - 1) >> 6;    // 781 (64-elem chunks)
constexpr int NCH_PAD = 784;
constexpr int MAXSEG = 4096;
constexpr int NGRP   = NELEM / 8;           // 6250
constexpr double DELTA_D = 1.0e-3;
constexpr double THETA_D = 1.0;
constexpr float  DECAY_F = 0.90483741803595957311f;  // float32(exp(-1/10))
}

struct WS {
    double2 rq[SLOTS];                        // (R_i, Q_i), R = Q - theta/P
    double  eAm[SLOTS], eAg[SLOTS], eAi[SLOTS];  // block-exclusive affine entries
    double  ePl[SLOTS], eQl[SLOTS];              // block-exclusive (p,q) entries
    double  gAm[64], gAg[64], gAi[64];           // 49 block aggregates (affine)
    double  gPp[64], gPq[64];                    // 49 block aggregates (p,q)
    double  gmaxR[1024];                         // per-64-chunk max R
    double  gbndQ[MAXSEG];
    int     gbnd[MAXSEG];
    int     gnseg;
    int     pad;
    float   swv[SLOTS];
    float   iwv[SLOTS];
};  // ~3.2 MB

// ---------------- K1: per-timestep weighted row sums (natural layout) ----------------
__global__ __launch_bounds__(256) void k_rowdot(
    const float* __restrict__ spikes,
    const float* __restrict__ w,
    const float* __restrict__ vrev,
    float* __restrict__ swv,
    float* __restrict__ iwv)
{
    const int lane = threadIdx.x & 63;
    const int wv   = threadIdx.x >> 6;
    const int rg   = blockIdx.x * 4 + wv;
    if (rg >= NGRP) return;
    const int row0 = rg * 8;

    const float4* __restrict__ w4 = reinterpret_cast<const float4*>(w);
    const float4* __restrict__ r4 = reinterpret_cast<const float4*>(vrev);
    const int j1 = lane;
    const int j2 = lane + 64;
    const bool has2 = (j2 < NQ4);
    float4 a1 = w4[j1], r1 = r4[j1];
    float4 aw1 = make_float4(fabsf(a1.x), fabsf(a1.y), fabsf(a1.z), fabsf(a1.w));
    float4 ar1 = make_float4(aw1.x * r1.x, aw1.y * r1.y, aw1.z * r1.z, aw1.w * r1.w);
    float4 aw2 = make_float4(0.f, 0.f, 0.f, 0.f), ar2 = aw2;
    if (has2) {
        float4 a2 = w4[j2], r2 = r4[j2];
        aw2 = make_float4(fabsf(a2.x), fabsf(a2.y), fabsf(a2.z), fabsf(a2.w));
        ar2 = make_float4(aw2.x * r2.x, aw2.y * r2.y, aw2.z * r2.z, aw2.w * r2.w);
    }

    float sp[8], ip[8];
#pragma unroll
    for (int r = 0; r < 8; ++r) {
        const float4* __restrict__ srow =
            reinterpret_cast<const float4*>(spikes + (size_t)(row0 + r) * NSYN);
        float4 s1 = srow[j1];
        float a = s1.x * aw1.x + s1.y * aw1.y + s1.z * aw1.z + s1.w * aw1.w;
        float b = s1.x * ar1.x + s1.y * ar1.y + s1.z * ar1.z + s1.w * ar1.w;
        if (has2) {
            float4 s2 = srow[j2];
            a += s2.x * aw2.x + s2.y * aw2.y + s2.z * aw2.z + s2.w * aw2.w;
            b += s2.x * ar2.x + s2.y * ar2.y + s2.z * ar2.z + s2.w * ar2.w;
        }
        sp[r] = a; ip[r] = b;
    }
#pragma unroll
    for (int d = 32; d > 0; d >>= 1) {
#pragma unroll
        for (int r = 0; r < 8; ++r) {
            sp[r] += __shfl_xor(sp[r], d);
            ip[r] += __shfl_xor(ip[r], d);
        }
    }
    if (lane == 0) {
        *reinterpret_cast<float4*>(swv + row0)     = make_float4(sp[0], sp[1], sp[2], sp[3]);
        *reinterpret_cast<float4*>(swv + row0 + 4) = make_float4(sp[4], sp[5], sp[6], sp[7]);
        *reinterpret_cast<float4*>(iwv + row0)     = make_float4(ip[0], ip[1], ip[2], ip[3]);
        *reinterpret_cast<float4*>(iwv + row0 + 4) = make_float4(ip[4], ip[5], ip[6], ip[7]);
    }
}

// ---------------- K2: block-local affine (m,g,i) scan, 49 blocks ----------------
__global__ __launch_bounds__(1024) void k_scanA(const float* __restrict__ swv,
                                                const float* __restrict__ iwv,
                                                WS* __restrict__ ws)
{
    const int tid = threadIdx.x, lane = tid & 63, wv = tid >> 6, blk = blockIdx.x;
    const int idx = blk * T + tid;
    const bool live = (idx < NELEM);
    const double decay = (double)DECAY_F;
    __shared__ double s_a[16], s_b[16], s_c[16];

    double s = live ? (double)swv[idx] : 0.0;
    double t = live ? (double)iwv[idx] : 0.0;
    double m_in = live ? decay : 1.0;
    double g_in = live ? s * decay : 0.0;
    double i_in = live ? t * decay : 0.0;
#pragma unroll
    for (int d = 1; d < 64; d <<= 1) {
        double pm = __shfl_up(m_in, d);
        double pg = __shfl_up(g_in, d);
        double pi = __shfl_up(i_in, d);
        if (lane >= d) {
            g_in = m_in * pg + g_in;
            i_in = m_in * pi + i_in;
            m_in = pm * m_in;
        }
    }
    if (lane == 63) { s_a[wv] = m_in; s_b[wv] = g_in; s_c[wv] = i_in; }
    __syncthreads();
    if (wv == 0) {
        double wm = (lane < 16) ? s_a[lane] : 1.0;
        double wg = (lane < 16) ? s_b[lane] : 0.0;
        double wi = (lane < 16) ? s_c[lane] : 0.0;
#pragma unroll
        for (int d = 1; d < 16; d <<= 1) {
            double pm = __shfl_up(wm, d);
            double pg = __shfl_up(wg, d);
            double pi = __shfl_up(wi, d);
            if (lane >= d) {
                wg = wm * pg + wg;
                wi = wm * pi + wi;
                wm = pm * wm;
            }
        }
        if (lane < 16) { s_a[lane] = wm; s_b[lane] = wg; s_c[lane] = wi; }
        if (lane == 15) { ws->gAm[blk] = wm; ws->gAg[blk] = wg; ws->gAi[blk] = wi; }
    }
    __syncthreads();
    double em = __shfl_up(m_in, 1), eg = __shfl_up(g_in, 1), ei = __shfl_up(i_in, 1);
    if (lane == 0) { em = 1.0; eg = 0.0; ei = 0.0; }
    if (wv > 0) {
        double qm = s_a[wv - 1], qg = s_b[wv - 1], qi = s_c[wv - 1];
        eg = em * qg + eg;
        ei = em * qi + ei;
        em = qm * em;
    }
    ws->eAm[idx] = em; ws->eAg[idx] = eg; ws->eAi[idx] = ei;
}

// ---------------- K3: redundant 49-aggregate affine scan + (p,q) block scan ----------------
__global__ __launch_bounds__(1024) void k_scanB(WS* __restrict__ ws)
{
    const int tid = threadIdx.x, lane = tid & 63, wv = tid >> 6, blk = blockIdx.x;
    const int idx = blk * T + tid;
    const bool live = (idx < NELEM);
    __shared__ double s_a[16], s_b[16];
    __shared__ double s_qg0, s_qi0;

    double em = ws->eAm[idx], eg = ws->eAg[idx], ei = ws->eAi[idx];

    // redundant scan of the 49 affine block aggregates (every block, wave 0)
    if (wv == 0) {
        double am = (lane < SBLK) ? ws->gAm[lane] : 1.0;
        double ag = (lane < SBLK) ? ws->gAg[lane] : 0.0;
        double ai = (lane < SBLK) ? ws->gAi[lane] : 0.0;
#pragma unroll
        for (int d = 1; d < 64; d <<= 1) {
            double pm = __shfl_up(am, d);
            double pg = __shfl_up(ag, d);
            double pi = __shfl_up(ai, d);
            if (lane >= d) {
                ag = am * pg + ag;
                ai = am * pi + ai;
                am = pm * am;
            }
        }
        double zg = __shfl_up(ag, 1), zi = __shfl_up(ai, 1);
        if (lane == 0) { zg = 0.0; zi = 0.0; }
        if (lane == blk) { s_qg0 = zg; s_qi0 = zi; }
    }
    __syncthreads();

    double Eg = em * s_qg0 + eg;        // global-exclusive exp traces entering idx
    double Ei = em * s_qi0 + ei;
    double p_in = 1.0, q_in = 0.0;
    if (live) {
        double aa = DELTA_D * (1.0 + Eg);
        double om = 1.0 - aa;
        p_in = om;
        q_in = (DELTA_D * Ei) / om;
    }
#pragma unroll
    for (int d = 1; d < 64; d <<= 1) {
        double pp = __shfl_up(p_in, d);
        double pq = __shfl_up(q_in, d);
        if (lane >= d) {
            q_in = pq + q_in / pp;
            p_in = pp * p_in;
        }
    }
    if (lane == 63) { s_a[wv] = p_in; s_b[wv] = q_in; }
    __syncthreads();
    if (wv == 0) {
        double wp = (lane < 16) ? s_a[lane] : 1.0;
        double wq = (lane < 16) ? s_b[lane] : 0.0;
#pragma unroll
        for (int d = 1; d < 16; d <<= 1) {
            double pp = __shfl_up(wp, d);
            double pq = __shfl_up(wq, d);
            if (lane >= d) {
                wq = pq + wq / pp;
                wp = pp * wp;
            }
        }
        if (lane < 16) { s_a[lane] = wp; s_b[lane] = wq; }
        if (lane == 15) { ws->gPp[blk] = wp; ws->gPq[blk] = wq; }
    }
    __syncthreads();
    double ep = __shfl_up(p_in, 1), eq = __shfl_up(q_in, 1);
    if (lane == 0) { ep = 1.0; eq = 0.0; }
    if (wv > 0) {
        double ap = s_a[wv - 1], aq = s_b[wv - 1];
        eq = aq + eq / ap;
        ep = ap * ep;
    }
    ws->ePl[idx] = ep; ws->eQl[idx] = eq;
}

// ---------------- K4: redundant 49-aggregate (p,q) scan + apply -> rq, chunk maxima ----------------
__global__ __launch_bounds__(1024) void k_apply(WS* __restrict__ ws)
{
    const int tid = threadIdx.x, lane = tid & 63, wv = tid >> 6, blk = blockIdx.x;
    const int idx = blk * T + tid;
    const bool live = (idx < NELEM);
    __shared__ double s_qp0, s_qq0;

    double pl = ws->ePl[idx], ql = ws->eQl[idx];

    if (wv == 0) {
        double ap = (lane < SBLK) ? ws->gPp[lane] : 1.0;
        double aq = (lane < SBLK) ? ws->gPq[lane] : 0.0;
#pragma unroll
        for (int d = 1; d < 64; d <<= 1) {
            double pp = __shfl_up(ap, d);
            double pq = __shfl_up(aq, d);
            if (lane >= d) {
                aq = pq + aq / pp;
                ap = pp * ap;
            }
        }
        double zp = __shfl_up(ap, 1), zq = __shfl_up(aq, 1);
        if (lane == 0) { zp = 1.0; zq = 0.0; }
        if (lane == blk) { s_qp0 = zp; s_qq0 = zq; }
    }
    __syncthreads();

    double Q = s_qq0 + ql / s_qp0;
    double P = s_qp0 * pl;
    double R = live ? (Q - THETA_D / P) : -1.0e308;
    ws->rq[idx] = make_double2(R, Q);
    double mR = R;
#pragma unroll
    for (int d = 32; d > 0; d >>= 1) mR = fmax(mR, __shfl_xor(mR, d));
    if (lane == 0) ws->gmaxR[idx >> 6] = mR;
}

// ---------------- K5: serial segment search (block 0) + parallel XCD0 prewarm ----------------
__global__ __launch_bounds__(1024) void k_search(WS* __restrict__ ws)
{
    const int tid = threadIdx.x, blk = blockIdx.x;

    if (blk == 0) {
        __shared__ double smax[NCH_PAD];
        for (int c = tid; c < NCH_PAD; c += T)
            smax[c] = (c <= CMAXC) ? ws->gmaxR[c] : -1.0e308;
        __syncthreads();

        if (tid < 64) {
            const int lane = tid;
            int nseg = 1;
            if (lane == 0) { ws->gbnd[0] = 0; ws->gbndQ[0] = 0.0; }
            double Qr = 0.0;
            int pos = 1;
            while (pos < NELEM && nseg < MAXSEG) {
                int c = pos >> 6;
                int i0 = -1;
                double Qnb = 0.0;
                while (true) {
                    int cf = -1;
                    for (int cb = c; cb <= CMAXC; cb += 64) {
                        int cc = cb + lane;
                        bool qy = (cc <= CMAXC) && (smax[cc] >= Qr);
                        unsigned long long m = __ballot(qy);
                        if (m) { cf = cb + __builtin_ctzll(m); break; }
                    }
                    if (cf < 0) break;
                    int i = (cf << 6) + lane;
                    bool valid = (i >= pos) && (i < NELEM);
                    double2 rv = valid ? ws->rq[i] : make_double2(-1.0e308, 0.0);
                    unsigned long long m2 = __ballot(valid && (rv.x >= Qr));
                    if (m2) {
                        int r = __builtin_ctzll(m2);
                        i0 = (cf << 6) + r;
                        if (r < 63) Qnb = __shfl(rv.y, r + 1);   // Q[i0+1] from same chunk load
                        break;
                    }
                    c = cf + 1;               // chunk max came from masked-out elems
                    if (c > CMAXC) break;
                }
                if (i0 < 0) break;
                int nb = i0 + 1;              // reset lands at nb
                if (nb >= NELEM) break;
                if ((i0 & 63) == 63) Qnb = ws->rq[nb].y;  // rare: boundary straddle
                Qr = Qnb;
                if (lane == 0) { ws->gbnd[nseg] = nb; ws->gbndQ[nseg] = Qr; }
                nseg++;
                pos = nb + 1;
            }
            if (lane == 0) ws->gnseg = nseg;
        } else {
            // block 0, tid>=64: prewarm stripe 0 of rq into this XCD's L2
            double acc = 0.0;
            for (int i = tid; i < NELEM; i += 7 * T) acc += ws->rq[i].x;
            asm volatile("" :: "v"((float)acc));
        }
    } else if ((blk & 7) == 0) {
        // blocks 8,16,24,32,40,48 land on the same XCD as block 0 -> parallel prewarm
        const int p = blk >> 3;
        double acc = 0.0;
        for (int i = p * T + tid; i < NELEM; i += 7 * T) acc += ws->rq[i].x;
        asm volatile("" :: "v"((float)acc));
    }
}

// ---------------- K6: parallel fill (P reconstructed from rq) ----------------
__global__ __launch_bounds__(1024) void k_fill(const WS* __restrict__ ws,
                                               float* __restrict__ out)
{
    __shared__ int    sb[MAXSEG];
    __shared__ double sq[MAXSEG];
    __shared__ int    s_nseg;
    const int tid = threadIdx.x;
    if (tid == 0) s_nseg = ws->gnseg;
    __syncthreads();
    const int nseg = s_nseg;
    for (int i = tid; i < nseg; i += T) { sb[i] = ws->gbnd[i]; sq[i] = ws->gbndQ[i]; }
    __syncthreads();

    const int idx = blockIdx.x * T + tid;
    if (idx < NELEM) {
        int lo = 0, hi = nseg - 1;
        while (lo < hi) {
            int mid = (lo + hi + 1) >> 1;
            if (sb[mid] <= idx) lo = mid; else hi = mid - 1;
        }
        if (idx == sb[lo]) {
            out[idx] = 0.0f;
        } else {
            double2 v = ws->rq[idx];
            double P = THETA_D / (v.y - v.x);        // Q - R = theta/P
            out[idx] = (float)(P * (v.y - sq[lo]));
        }
    }
}

extern "C" void kernel_launch(void* const* d_in, const int* in_sizes, int n_in,
                              void* d_out, int out_size, void* d_ws, size_t ws_size,
                              hipStream_t stream) {
    const float* spikes = (const float*)d_in[0];
    const float* w      = (const float*)d_in[1];
    const float* vrev   = (const float*)d_in[2];
    float* out = (float*)d_out;
    WS* ws = (WS*)d_ws;

    hipLaunchKernelGGL(k_rowdot, dim3((NGRP + 3) / 4), dim3(256), 0, stream,
                       spikes, w, vrev, ws->swv, ws->iwv);
    hipLaunchKernelGGL(k_scanA,  dim3(SBLK), dim3(T), 0, stream, ws->swv, ws->iwv, ws);
    hipLaunchKernelGGL(k_scanB,  dim3(SBLK), dim3(T), 0, stream, ws);
    hipLaunchKernelGGL(k_apply,  dim3(SBLK), dim3(T), 0, stream, ws);
    hipLaunchKernelGGL(k_search, dim3(56),   dim3(T), 0, stream, ws);
    hipLaunchKernelGGL(k_fill,   dim3(SBLK), dim3(T), 0, stream, ws, out);
}

// Round 3
// 194.880 us; speedup vs baseline: 1.2015x; 1.0108x over previous
//
#include <hip/hip_runtime.h>
#include <cmath>

namespace {
constexpr int NELEM  = 50000;
constexpr int NSYN   = 500;
constexpr int NQ4    = 125;                 // NSYN/4
constexpr int T      = 1024;
constexpr int SBLK   = 49;                  // 49*1024 = 50176 >= NELEM
constexpr int SLOTS  = SBLK * T;            // 50176
constexpr int CMAXC  = (NELEM - 1) >> 6;    // 781 (64-elem chunks)
constexpr int NCH_PAD = 784;
constexpr int MAXSEG = 4096;
constexpr int NGRP   = NELEM / 8;           // 6250
constexpr double DELTA_D = 1.0e-3;
constexpr double THETA_D = 1.0;
constexpr float  DECAY_F = 0.90483741803595957311f;  // float32(exp(-1/10))
}

struct WS {
    double2 rq[SLOTS];                       // (R_i, Q_i), R = Q - theta/P
    double  gAm[64], gAg[64], gAi[64];       // 49 block aggregates (affine)
    double  gPp[64], gPq[64];                // 49 block aggregates (p,q)
    double  gmaxR[1024];                     // per-64-chunk max R
    double  gbndQ[MAXSEG];
    int     gbnd[MAXSEG];
    int     gnseg;
    int     flagA[64];                       // lookback flags (zeroed by k_rowdot)
    int     flagB[64];
    float   swv[SLOTS];
    float   iwv[SLOTS];
};  // ~1.3 MB

__device__ inline void pub_d(double* p, double v) {
    __hip_atomic_store(reinterpret_cast<unsigned long long*>(p),
                       __double_as_longlong(v),
                       __ATOMIC_RELAXED, __HIP_MEMORY_SCOPE_AGENT);
}
__device__ inline double rd_d(const double* p) {
    unsigned long long u =
        __hip_atomic_load(reinterpret_cast<const unsigned long long*>(p),
                          __ATOMIC_RELAXED, __HIP_MEMORY_SCOPE_AGENT);
    return __longlong_as_double(u);
}

// ---------------- K1: per-timestep weighted row sums (+ flag reset) ----------------
__global__ __launch_bounds__(256) void k_rowdot(
    const float* __restrict__ spikes,
    const float* __restrict__ w,
    const float* __restrict__ vrev,
    WS* __restrict__ ws)
{
    // zero lookback flags for this iteration (workspace is re-poisoned between runs)
    if (blockIdx.x == 0 && threadIdx.x < 128) {
        const int l = threadIdx.x;
        if (l < 64) ws->flagA[l] = 0; else ws->flagB[l - 64] = 0;
    }

    const int lane = threadIdx.x & 63;
    const int wv   = threadIdx.x >> 6;
    const int rg   = blockIdx.x * 4 + wv;
    if (rg >= NGRP) return;
    const int row0 = rg * 8;

    const float4* __restrict__ w4 = reinterpret_cast<const float4*>(w);
    const float4* __restrict__ r4 = reinterpret_cast<const float4*>(vrev);
    const int j1 = lane;
    const int j2 = lane + 64;
    const bool has2 = (j2 < NQ4);
    float4 a1 = w4[j1], r1 = r4[j1];
    float4 aw1 = make_float4(fabsf(a1.x), fabsf(a1.y), fabsf(a1.z), fabsf(a1.w));
    float4 ar1 = make_float4(aw1.x * r1.x, aw1.y * r1.y, aw1.z * r1.z, aw1.w * r1.w);
    float4 aw2 = make_float4(0.f, 0.f, 0.f, 0.f), ar2 = aw2;
    if (has2) {
        float4 a2 = w4[j2], r2 = r4[j2];
        aw2 = make_float4(fabsf(a2.x), fabsf(a2.y), fabsf(a2.z), fabsf(a2.w));
        ar2 = make_float4(aw2.x * r2.x, aw2.y * r2.y, aw2.z * r2.z, aw2.w * r2.w);
    }

    float sp[8], ip[8];
#pragma unroll
    for (int r = 0; r < 8; ++r) {
        const float4* __restrict__ srow =
            reinterpret_cast<const float4*>(spikes + (size_t)(row0 + r) * NSYN);
        float4 s1 = srow[j1];
        float a = s1.x * aw1.x + s1.y * aw1.y + s1.z * aw1.z + s1.w * aw1.w;
        float b = s1.x * ar1.x + s1.y * ar1.y + s1.z * ar1.z + s1.w * ar1.w;
        if (has2) {
            float4 s2 = srow[j2];
            a += s2.x * aw2.x + s2.y * aw2.y + s2.z * aw2.z + s2.w * aw2.w;
            b += s2.x * ar2.x + s2.y * ar2.y + s2.z * ar2.z + s2.w * ar2.w;
        }
        sp[r] = a; ip[r] = b;
    }
#pragma unroll
    for (int d = 32; d > 0; d >>= 1) {
#pragma unroll
        for (int r = 0; r < 8; ++r) {
            sp[r] += __shfl_xor(sp[r], d);
            ip[r] += __shfl_xor(ip[r], d);
        }
    }
    if (lane == 0) {
        *reinterpret_cast<float4*>(ws->swv + row0)     = make_float4(sp[0], sp[1], sp[2], sp[3]);
        *reinterpret_cast<float4*>(ws->swv + row0 + 4) = make_float4(sp[4], sp[5], sp[6], sp[7]);
        *reinterpret_cast<float4*>(ws->iwv + row0)     = make_float4(ip[0], ip[1], ip[2], ip[3]);
        *reinterpret_cast<float4*>(ws->iwv + row0 + 4) = make_float4(ip[4], ip[5], ip[6], ip[7]);
    }
}

// ---------------- K2: fused scans via decoupled lookback (49 co-resident blocks) ----------------
__global__ __launch_bounds__(1024) void k_scan(WS* __restrict__ ws)
{
    const int tid = threadIdx.x, lane = tid & 63, wv = tid >> 6, blk = blockIdx.x;
    const int idx = blk * T + tid;
    const bool live = (idx < NELEM);
    const double decay = (double)DECAY_F;
    __shared__ double s_a[16], s_b[16], s_c[16];
    __shared__ double s_qg0, s_qi0, s_qp0, s_qq0;

    // ---- A: affine (m,g,i) 64-wide wave scan ----
    double s = live ? (double)ws->swv[idx] : 0.0;
    double t = live ? (double)ws->iwv[idx] : 0.0;
    double m_in = live ? decay : 1.0;
    double g_in = live ? s * decay : 0.0;
    double i_in = live ? t * decay : 0.0;
#pragma unroll
    for (int d = 1; d < 64; d <<= 1) {
        double pm = __shfl_up(m_in, d);
        double pg = __shfl_up(g_in, d);
        double pi = __shfl_up(i_in, d);
        if (lane >= d) {
            g_in = m_in * pg + g_in;
            i_in = m_in * pi + i_in;
            m_in = pm * m_in;
        }
    }
    if (lane == 63) { s_a[wv] = m_in; s_b[wv] = g_in; s_c[wv] = i_in; }
    __syncthreads();

    // ---- B: wave0 scans 16 wave-aggregates, publishes block aggregate, lookback ----
    if (wv == 0) {
        double wm = (lane < 16) ? s_a[lane] : 1.0;
        double wg = (lane < 16) ? s_b[lane] : 0.0;
        double wi = (lane < 16) ? s_c[lane] : 0.0;
#pragma unroll
        for (int d = 1; d < 16; d <<= 1) {
            double pm = __shfl_up(wm, d);
            double pg = __shfl_up(wg, d);
            double pi = __shfl_up(wi, d);
            if (lane >= d) {
                wg = wm * pg + wg;
                wi = wm * pi + wi;
                wm = pm * wm;
            }
        }
        if (lane < 16) { s_a[lane] = wm; s_b[lane] = wg; s_c[lane] = wi; }
        if (lane == 15) {
            pub_d(&ws->gAm[blk], wm); pub_d(&ws->gAg[blk], wg); pub_d(&ws->gAi[blk], wi);
            __hip_atomic_store(&ws->flagA[blk], 1, __ATOMIC_RELEASE, __HIP_MEMORY_SCOPE_AGENT);
        }
        // lookback: gather all 49 published affine aggregates
        double am = 1.0, ag = 0.0, ai = 0.0;
        if (lane < SBLK) {
            while (__hip_atomic_load(&ws->flagA[lane], __ATOMIC_ACQUIRE,
                                     __HIP_MEMORY_SCOPE_AGENT) == 0)
                __builtin_amdgcn_s_sleep(1);
            am = rd_d(&ws->gAm[lane]); ag = rd_d(&ws->gAg[lane]); ai = rd_d(&ws->gAi[lane]);
        }
#pragma unroll
        for (int d = 1; d < 64; d <<= 1) {
            double pm = __shfl_up(am, d);
            double pg = __shfl_up(ag, d);
            double pi = __shfl_up(ai, d);
            if (lane >= d) {
                ag = am * pg + ag;
                ai = am * pi + ai;
                am = pm * am;
            }
        }
        double zg = __shfl_up(ag, 1), zi = __shfl_up(ai, 1);
        if (lane == 0) { zg = 0.0; zi = 0.0; }
        if (lane == blk) { s_qg0 = zg; s_qi0 = zi; }
    }
    __syncthreads();

    // ---- C: per-thread block-exclusive affine entry, global exp traces, (p,q) init ----
    double em = __shfl_up(m_in, 1), eg = __shfl_up(g_in, 1), ei = __shfl_up(i_in, 1);
    if (lane == 0) { em = 1.0; eg = 0.0; ei = 0.0; }
    if (wv > 0) {
        double qm = s_a[wv - 1], qg = s_b[wv - 1], qi = s_c[wv - 1];
        eg = em * qg + eg;
        ei = em * qi + ei;
        em = qm * em;
    }
    double Eg = em * s_qg0 + eg;        // global-exclusive exp traces entering idx
    double Ei = em * s_qi0 + ei;
    double p_in = 1.0, q_in = 0.0;
    if (live) {
        double aa = DELTA_D * (1.0 + Eg);
        double om = 1.0 - aa;
        p_in = om;
        q_in = (DELTA_D * Ei) / om;
    }
    __syncthreads();                    // protect s_a/s_b reuse below

    // ---- D: (p,q) 64-wide wave scan ----
#pragma unroll
    for (int d = 1; d < 64; d <<= 1) {
        double pp = __shfl_up(p_in, d);
        double pq = __shfl_up(q_in, d);
        if (lane >= d) {
            q_in = pq + q_in / pp;
            p_in = pp * p_in;
        }
    }
    if (lane == 63) { s_a[wv] = p_in; s_b[wv] = q_in; }
    __syncthreads();

    // ---- E: wave0 scans 16 wave-aggregates, publishes, lookback ----
    if (wv == 0) {
        double wp = (lane < 16) ? s_a[lane] : 1.0;
        double wq = (lane < 16) ? s_b[lane] : 0.0;
#pragma unroll
        for (int d = 1; d < 16; d <<= 1) {
            double pp = __shfl_up(wp, d);
            double pq = __shfl_up(wq, d);
            if (lane >= d) {
                wq = pq + wq / pp;
                wp = pp * wp;
            }
        }
        if (lane < 16) { s_a[lane] = wp; s_b[lane] = wq; }
        if (lane == 15) {
            pub_d(&ws->gPp[blk], wp); pub_d(&ws->gPq[blk], wq);
            __hip_atomic_store(&ws->flagB[blk], 1, __ATOMIC_RELEASE, __HIP_MEMORY_SCOPE_AGENT);
        }
        double ap = 1.0, aq = 0.0;
        if (lane < SBLK) {
            while (__hip_atomic_load(&ws->flagB[lane], __ATOMIC_ACQUIRE,
                                     __HIP_MEMORY_SCOPE_AGENT) == 0)
                __builtin_amdgcn_s_sleep(1);
            ap = rd_d(&ws->gPp[lane]); aq = rd_d(&ws->gPq[lane]);
        }
#pragma unroll
        for (int d = 1; d < 64; d <<= 1) {
            double pp = __shfl_up(ap, d);
            double pq = __shfl_up(aq, d);
            if (lane >= d) {
                aq = pq + aq / pp;
                ap = pp * ap;
            }
        }
        double zp = __shfl_up(ap, 1), zq = __shfl_up(aq, 1);
        if (lane == 0) { zp = 1.0; zq = 0.0; }
        if (lane == blk) { s_qp0 = zp; s_qq0 = zq; }
    }
    __syncthreads();

    // ---- F: apply -> rq, chunk maxima ----
    double ep = __shfl_up(p_in, 1), eq = __shfl_up(q_in, 1);
    if (lane == 0) { ep = 1.0; eq = 0.0; }
    if (wv > 0) {
        double ap2 = s_a[wv - 1], aq2 = s_b[wv - 1];
        eq = aq2 + eq / ap2;
        ep = ap2 * ep;
    }
    double Q = s_qq0 + eq / s_qp0;
    double P = s_qp0 * ep;
    double R = live ? (Q - THETA_D / P) : -1.0e308;
    ws->rq[idx] = make_double2(R, Q);
    double mR = R;
#pragma unroll
    for (int d = 32; d > 0; d >>= 1) mR = fmax(mR, __shfl_xor(mR, d));
    if (lane == 0) ws->gmaxR[idx >> 6] = mR;
}

// ---------------- K3: serial segment search (block 0) + parallel XCD0 prewarm ----------------
__global__ __launch_bounds__(1024) void k_search(WS* __restrict__ ws)
{
    const int tid = threadIdx.x, blk = blockIdx.x;

    if (blk == 0) {
        __shared__ double smax[NCH_PAD];
        for (int c = tid; c < NCH_PAD; c += T)
            smax[c] = (c <= CMAXC) ? ws->gmaxR[c] : -1.0e308;
        __syncthreads();

        if (tid < 64) {
            const int lane = tid;
            int nseg = 1;
            if (lane == 0) { ws->gbnd[0] = 0; ws->gbndQ[0] = 0.0; }
            double Qr = 0.0;
            int pos = 1;
            while (pos < NELEM && nseg < MAXSEG) {
                int c = pos >> 6;
                int i0 = -1;
                double Qnb = 0.0;
                while (true) {
                    int cf = -1;
                    for (int cb = c; cb <= CMAXC; cb += 64) {
                        int cc = cb + lane;
                        bool qy = (cc <= CMAXC) && (smax[cc] >= Qr);
                        unsigned long long m = __ballot(qy);
                        if (m) { cf = cb + __builtin_ctzll(m); break; }
                    }
                    if (cf < 0) break;
                    int i = (cf << 6) + lane;
                    bool valid = (i >= pos) && (i < NELEM);
                    double2 rv = valid ? ws->rq[i] : make_double2(-1.0e308, 0.0);
                    unsigned long long m2 = __ballot(valid && (rv.x >= Qr));
                    if (m2) {
                        int r = __builtin_ctzll(m2);
                        i0 = (cf << 6) + r;
                        if (r < 63) Qnb = __shfl(rv.y, r + 1);   // Q[i0+1] from same chunk load
                        break;
                    }
                    c = cf + 1;               // chunk max came from masked-out elems
                    if (c > CMAXC) break;
                }
                if (i0 < 0) break;
                int nb = i0 + 1;              // reset lands at nb
                if (nb >= NELEM) break;
                if ((i0 & 63) == 63) Qnb = ws->rq[nb].y;  // rare: boundary straddle
                Qr = Qnb;
                if (lane == 0) { ws->gbnd[nseg] = nb; ws->gbndQ[nseg] = Qr; }
                nseg++;
                pos = nb + 1;
            }
            if (lane == 0) ws->gnseg = nseg;
        } else {
            // block 0, tid>=64: prewarm stripe 0 of rq into this XCD's L2
            double acc = 0.0;
            for (int i = tid; i < NELEM; i += 7 * T) acc += ws->rq[i].x;
            asm volatile("" :: "v"((float)acc));
        }
    } else if ((blk & 7) == 0) {
        // blocks 8,16,24,32,40,48 land on the same XCD as block 0 -> parallel prewarm
        const int p = blk >> 3;
        double acc = 0.0;
        for (int i = p * T + tid; i < NELEM; i += 7 * T) acc += ws->rq[i].x;
        asm volatile("" :: "v"((float)acc));
    }
}

// ---------------- K4: parallel fill (P reconstructed from rq) ----------------
__global__ __launch_bounds__(1024) void k_fill(const WS* __restrict__ ws,
                                               float* __restrict__ out)
{
    __shared__ int    sb[MAXSEG];
    __shared__ double sq[MAXSEG];
    __shared__ int    s_nseg;
    const int tid = threadIdx.x;
    if (tid == 0) s_nseg = ws->gnseg;
    __syncthreads();
    const int nseg = s_nseg;
    for (int i = tid; i < nseg; i += T) { sb[i] = ws->gbnd[i]; sq[i] = ws->gbndQ[i]; }
    __syncthreads();

    const int idx = blockIdx.x * T + tid;
    if (idx < NELEM) {
        int lo = 0, hi = nseg - 1;
        while (lo < hi) {
            int mid = (lo + hi + 1) >> 1;
            if (sb[mid] <= idx) lo = mid; else hi = mid - 1;
        }
        if (idx == sb[lo]) {
            out[idx] = 0.0f;
        } else {
            double2 v = ws->rq[idx];
            double P = THETA_D / (v.y - v.x);        // Q - R = theta/P
            out[idx] = (float)(P * (v.y - sq[lo]));
        }
    }
}

extern "C" void kernel_launch(void* const* d_in, const int* in_sizes, int n_in,
                              void* d_out, int out_size, void* d_ws, size_t ws_size,
                              hipStream_t stream) {
    const float* spikes = (const float*)d_in[0];
    const float* w      = (const float*)d_in[1];
    const float* vrev   = (const float*)d_in[2];
    float* out = (float*)d_out;
    WS* ws = (WS*)d_ws;

    hipLaunchKernelGGL(k_rowdot, dim3((NGRP + 3) / 4), dim3(256), 0, stream,
                       spikes, w, vrev, ws);
    hipLaunchKernelGGL(k_scan,   dim3(SBLK), dim3(T), 0, stream, ws);
    hipLaunchKernelGGL(k_search, dim3(56),   dim3(T), 0, stream, ws);
    hipLaunchKernelGGL(k_fill,   dim3(SBLK), dim3(T), 0, stream, ws, out);
}